// Round 2
// baseline (2112.818 us; speedup 1.0000x reference)
//
#include <hip/hip_runtime.h>
#include <hip/hip_bf16.h>
#include <math.h>

#define BSZ 4
#define CH  192
#define NPT 4096
#define KNB 16
#define KPF 24

__device__ __forceinline__ float gelu_exact(float x){
    return 0.5f * x * (1.0f + erff(x * 0.70710678118654752440f));
}

// ---------------- fp32 GEMM: out[b,o,n] = sum_c W[o,c] * in[b,c,n] (+bias)(+BN-fold)(+resid) ----
template<int KDIM, bool BIASED, bool SCALED, bool RESID>
__global__ __launch_bounds__(256) void k_gemm(
    const float* __restrict__ in, const float* __restrict__ W,
    const float* __restrict__ bias, const float* __restrict__ sc,
    const float* __restrict__ sh, const float* __restrict__ resid,
    float* __restrict__ out)
{
    constexpr int OT = 8, NT = 4;
    __shared__ float wtT[KDIM][OT];
    __shared__ float scl[SCALED ? KDIM : 1];
    __shared__ float shl[SCALED ? KDIM : 1];
    const int tid = threadIdx.x;
    const int o0  = blockIdx.y * OT;
    const int b   = blockIdx.z;
    const int n   = blockIdx.x * (256 * NT) + tid * NT;

    for (int lin = tid; lin < KDIM * OT; lin += 256){
        int c = lin >> 3, o = lin & 7;
        wtT[c][o] = W[(size_t)(o0 + o) * KDIM + c];
    }
    if (SCALED){
        for (int c = tid; c < KDIM; c += 256){ scl[c] = sc[c]; shl[c] = sh[c]; }
    }
    __syncthreads();

    float acc[OT][NT] = {};
    const float* ip = in + (size_t)b * KDIM * NPT + n;
    #pragma unroll 2
    for (int c = 0; c < KDIM; ++c){
        float4 x4 = *reinterpret_cast<const float4*>(ip + (size_t)c * NPT);
        float xv[NT] = {x4.x, x4.y, x4.z, x4.w};
        if (SCALED){
            #pragma unroll
            for (int j = 0; j < NT; ++j) xv[j] = fmaf(xv[j], scl[c], shl[c]);
        }
        float4 w0 = *reinterpret_cast<const float4*>(&wtT[c][0]);
        float4 w1 = *reinterpret_cast<const float4*>(&wtT[c][4]);
        float wv[OT] = {w0.x, w0.y, w0.z, w0.w, w1.x, w1.y, w1.z, w1.w};
        #pragma unroll
        for (int oo = 0; oo < OT; ++oo)
            #pragma unroll
            for (int j = 0; j < NT; ++j)
                acc[oo][j] = fmaf(wv[oo], xv[j], acc[oo][j]);
    }

    #pragma unroll
    for (int oo = 0; oo < OT; ++oo){
        size_t off = ((size_t)b * CH + o0 + oo) * NPT + n;
        float add = BIASED ? bias[o0 + oo] : 0.0f;
        float vals[4];
        #pragma unroll
        for (int j = 0; j < 4; ++j) vals[j] = acc[oo][j] + add;
        if (RESID){
            float4 r4 = *reinterpret_cast<const float4*>(resid + off);
            vals[0] += r4.x; vals[1] += r4.y; vals[2] += r4.z; vals[3] += r4.w;
        }
        float4 o4; o4.x = vals[0]; o4.y = vals[1]; o4.z = vals[2]; o4.w = vals[3];
        *reinterpret_cast<float4*>(out + off) = o4;
    }
}

// ---------------- fc1 with f64 accumulation: writes fp32 t1 and f64 t1 --------------------------
__global__ __launch_bounds__(256) void k_fc1_f64(
    const float* __restrict__ in, const float* __restrict__ W,
    float* __restrict__ outf, double* __restrict__ outd)
{
    constexpr int OT = 8, NT = 4;
    __shared__ float wtT[CH][OT];
    const int tid = threadIdx.x;
    const int o0  = blockIdx.y * OT;
    const int b   = blockIdx.z;
    const int n   = blockIdx.x * (256 * NT) + tid * NT;

    for (int lin = tid; lin < CH * OT; lin += 256){
        int c = lin >> 3, o = lin & 7;
        wtT[c][o] = W[(size_t)(o0 + o) * CH + c];
    }
    __syncthreads();

    double acc[OT][NT] = {};
    const float* ip = in + (size_t)b * CH * NPT + n;
    for (int c = 0; c < CH; ++c){
        float4 x4 = *reinterpret_cast<const float4*>(ip + (size_t)c * NPT);
        double xv[NT] = {x4.x, x4.y, x4.z, x4.w};
        float4 w0 = *reinterpret_cast<const float4*>(&wtT[c][0]);
        float4 w1 = *reinterpret_cast<const float4*>(&wtT[c][4]);
        double wv[OT] = {w0.x, w0.y, w0.z, w0.w, w1.x, w1.y, w1.z, w1.w};
        #pragma unroll
        for (int oo = 0; oo < OT; ++oo)
            #pragma unroll
            for (int j = 0; j < NT; ++j)
                acc[oo][j] = fma(wv[oo], xv[j], acc[oo][j]);
    }

    #pragma unroll
    for (int oo = 0; oo < OT; ++oo){
        size_t off = ((size_t)b * CH + o0 + oo) * NPT + n;
        #pragma unroll
        for (int j = 0; j < 4; ++j){
            outf[off + j] = (float)acc[oo][j];
            outd[off + j] = acc[oo][j];
        }
    }
}

// ---------------- f64 BN0 stats: fp32 scale/shift for downstream + f64 scale for kNN ------------
__global__ __launch_bounds__(256) void k_stats_f64(
    const double* __restrict__ t, const float* __restrict__ gamma,
    const float* __restrict__ beta, float* __restrict__ scale,
    float* __restrict__ shift, double* __restrict__ scd)
{
    const int c = blockIdx.x, tid = threadIdx.x;
    double s = 0., s2 = 0.;
    for (int b = 0; b < BSZ; ++b){
        const double* p = t + ((size_t)b * CH + c) * NPT;
        for (int n = tid; n < NPT; n += 256){ double v = p[n]; s += v; s2 += v * v; }
    }
    __shared__ double rs[256], rs2[256];
    rs[tid] = s; rs2[tid] = s2; __syncthreads();
    for (int off = 128; off; off >>= 1){
        if (tid < off){ rs[tid] += rs[tid + off]; rs2[tid] += rs2[tid + off]; }
        __syncthreads();
    }
    if (tid == 0){
        const double invn = 1.0 / (BSZ * NPT);
        double mean = rs[0] * invn;
        double var  = rs2[0] * invn - mean * mean;
        double rstd = 1.0 / sqrt(var + 1e-5);
        double s_   = rstd * (double)gamma[c];
        scale[c] = (float)s_;
        shift[c] = (float)((double)beta[c] - mean * s_);
        scd[c]   = s_;
    }
}

// ---------------- fp32 per-channel batch stats -> scale/shift -----------------------------------
__global__ __launch_bounds__(256) void k_stats(
    const float* __restrict__ t, const float* __restrict__ gamma,
    const float* __restrict__ beta, float* __restrict__ scale, float* __restrict__ shift)
{
    const int c = blockIdx.x, tid = threadIdx.x;
    float s = 0.f, s2 = 0.f;
    for (int b = 0; b < BSZ; ++b){
        const float* p = t + ((size_t)b * CH + c) * NPT;
        for (int n = tid; n < NPT; n += 256){ float v = p[n]; s += v; s2 += v * v; }
    }
    __shared__ float rs[256], rs2[256];
    rs[tid] = s; rs2[tid] = s2; __syncthreads();
    for (int off = 128; off; off >>= 1){
        if (tid < off){ rs[tid] += rs[tid + off]; rs2[tid] += rs2[tid + off]; }
        __syncthreads();
    }
    if (tid == 0){
        const float invn = 1.0f / (BSZ * NPT);
        float mean = rs[0] * invn;
        float var  = rs2[0] * invn - mean * mean;
        float rstd = rsqrtf(var + 1e-5f);
        float s_   = rstd * gamma[c];
        scale[c] = s_;
        shift[c] = beta[c] - mean * s_;
    }
}

// ---------------- transpose + per-channel f64 scale ---------------------------------------------
__global__ void k_tr64(const double* __restrict__ t1d, const double* __restrict__ scd,
                       double* __restrict__ featT)
{
    __shared__ double tile[32][33];
    const int n0 = blockIdx.x * 32, c0 = blockIdx.y * 32, b = blockIdx.z;
    #pragma unroll
    for (int r = 0; r < 32; r += 8){
        int c = c0 + threadIdx.y + r, n = n0 + threadIdx.x;
        tile[threadIdx.y + r][threadIdx.x] = t1d[((size_t)b * CH + c) * NPT + n] * scd[c];
    }
    __syncthreads();
    #pragma unroll
    for (int r = 0; r < 32; r += 8){
        int n = n0 + threadIdx.y + r, c = c0 + threadIdx.x;
        featT[((size_t)b * NPT + n) * CH + c] = tile[threadIdx.x][threadIdx.y + r];
    }
}

// ---------------- elementwise BN apply / double-GELU(BN) ----------------------------------------
__global__ __launch_bounds__(256) void k_affine(
    const float* __restrict__ in, const float* __restrict__ sc,
    const float* __restrict__ sh, float* __restrict__ out)
{
    const int c = blockIdx.y, b = blockIdx.z;
    const int n = (blockIdx.x * 256 + threadIdx.x) * 4;
    size_t i = ((size_t)b * CH + c) * NPT + n;
    float4 v = *reinterpret_cast<const float4*>(in + i);
    float s = sc[c], t = sh[c];
    float4 o;
    o.x = fmaf(v.x, s, t); o.y = fmaf(v.y, s, t);
    o.z = fmaf(v.z, s, t); o.w = fmaf(v.w, s, t);
    *reinterpret_cast<float4*>(out + i) = o;
}

__global__ __launch_bounds__(256) void k_u(
    const float* __restrict__ in, const float* __restrict__ sc,
    const float* __restrict__ sh, float* __restrict__ out)
{
    const int c = blockIdx.y, b = blockIdx.z;
    const int n = (blockIdx.x * 256 + threadIdx.x) * 4;
    size_t i = ((size_t)b * CH + c) * NPT + n;
    float4 v = *reinterpret_cast<const float4*>(in + i);
    float s = sc[c], t = sh[c];
    float4 o;
    o.x = gelu_exact(gelu_exact(fmaf(v.x, s, t)));
    o.y = gelu_exact(gelu_exact(fmaf(v.y, s, t)));
    o.z = gelu_exact(gelu_exact(fmaf(v.z, s, t)));
    o.w = gelu_exact(gelu_exact(fmaf(v.w, s, t)));
    *reinterpret_cast<float4*>(out + i) = o;
}

// ---------------- fp32 squared norms ------------------------------------------------------------
__global__ __launch_bounds__(256) void k_sq(const float* __restrict__ hbn, float* __restrict__ sqv)
{
    const int n = blockIdx.x * 256 + threadIdx.x;
    const int b = blockIdx.y;
    const float* p = hbn + (size_t)b * CH * NPT + n;
    float s = 0.f;
    #pragma unroll 4
    for (int c = 0; c < CH; ++c){ float v = p[(size_t)c * NPT]; s = fmaf(v, v, s); }
    sqv[b * NPT + n] = s;
}

// ---------------- fp32 prefilter kNN: top-24 candidates -----------------------------------------
__global__ __launch_bounds__(256) void k_knn24(
    const float* __restrict__ hbn, const float* __restrict__ sqv, int* __restrict__ idxout)
{
    __shared__ float qfT[CH][16];
    __shared__ float dtile[16][257];
    const int tid = threadIdx.x;
    const int b   = blockIdx.y;
    const int n0  = blockIdx.x * 16;
    const float* base = hbn + (size_t)b * CH * NPT;

    for (int lin = tid; lin < CH * 16; lin += 256){
        int c = lin >> 4, q = lin & 15;
        qfT[c][q] = base[(size_t)c * NPT + n0 + q];
    }
    __syncthreads();

    const int mg = tid & 63;
    const int qg = tid >> 6;
    const int qs = tid >> 4;
    const int ss = tid & 15;

    float lv[KPF]; int li[KPF];
    #pragma unroll
    for (int e = 0; e < KPF; ++e){ lv[e] = INFINITY; li[e] = 0x7fffffff; }
    float mv = INFINITY; int mi = 0x7fffffff, mp = 0;

    for (int chunk = 0; chunk < NPT / 256; ++chunk){
        const int m0 = chunk * 256 + mg * 4;
        float acc[4][4] = {};
        const float* fp = base + m0;
        #pragma unroll 2
        for (int c = 0; c < CH; ++c){
            float4 f4 = *reinterpret_cast<const float4*>(fp + (size_t)c * NPT);
            float4 q4 = *reinterpret_cast<const float4*>(&qfT[c][qg * 4]);
            float fm[4] = {f4.x, f4.y, f4.z, f4.w};
            float qv[4] = {q4.x, q4.y, q4.z, q4.w};
            #pragma unroll
            for (int a = 0; a < 4; ++a)
                #pragma unroll
                for (int m = 0; m < 4; ++m)
                    acc[a][m] = fmaf(qv[a], fm[m], acc[a][m]);
        }
        float4 s4 = *reinterpret_cast<const float4*>(sqv + b * NPT + m0);
        float sm[4] = {s4.x, s4.y, s4.z, s4.w};
        #pragma unroll
        for (int a = 0; a < 4; ++a)
            #pragma unroll
            for (int m = 0; m < 4; ++m)
                dtile[qg * 4 + a][mg * 4 + m] = fmaf(-2.0f, acc[a][m], sm[m]);
        __syncthreads();

        #pragma unroll
        for (int j = 0; j < 16; ++j){
            float v = dtile[qs][ss + 16 * j];
            int   i = chunk * 256 + ss + 16 * j;
            bool better = (v < mv) || (v == mv && i < mi);
            if (better){
                #pragma unroll
                for (int e = 0; e < KPF; ++e) if (e == mp){ lv[e] = v; li[e] = i; }
                mv = lv[0]; mi = li[0]; mp = 0;
                #pragma unroll
                for (int e = 1; e < KPF; ++e){
                    bool worse = (lv[e] > mv) || (lv[e] == mv && li[e] > mi);
                    if (worse){ mv = lv[e]; mi = li[e]; mp = e; }
                }
            }
        }
        __syncthreads();
    }

    const int nq = n0 + qs;
    for (int r = 0; r < KPF; ++r){
        float bv = INFINITY; int bi = 0x7fffffff;
        #pragma unroll
        for (int e = 0; e < KPF; ++e){
            bool better = (lv[e] < bv) || (lv[e] == bv && li[e] < bi);
            if (better){ bv = lv[e]; bi = li[e]; }
        }
        #pragma unroll
        for (int off = 8; off; off >>= 1){
            float ov = __shfl_xor(bv, off, 16);
            int   oi = __shfl_xor(bi, off, 16);
            if (ov < bv || (ov == bv && oi < bi)){ bv = ov; bi = oi; }
        }
        #pragma unroll
        for (int e = 0; e < KPF; ++e) if (li[e] == bi){ lv[e] = INFINITY; li[e] = 0x7fffffff; }
        if (ss == 0) idxout[((size_t)b * NPT + nq) * KPF + r] = bi;
    }
}

// ---------------- f64 re-rank of 24 candidates -> exact top-16 ----------------------------------
__global__ __launch_bounds__(64) void k_refine(
    const double* __restrict__ featT, const int* __restrict__ idx24, int* __restrict__ idxf)
{
    const int q = blockIdx.x, b = blockIdx.y, lane = threadIdx.x;
    const double* qv = featT + ((size_t)b * NPT + q) * CH;
    double q0 = qv[lane], q1 = qv[lane + 64], q2 = qv[lane + 128];
    double myd = INFINITY; int mym = 0x7fffffff;
    const int* cl = idx24 + ((size_t)b * NPT + q) * KPF;
    for (int t = 0; t < KPF; ++t){
        int m = cl[t];
        const double* cv = featT + ((size_t)b * NPT + m) * CH;
        double d0 = cv[lane] - q0, d1 = cv[lane + 64] - q1, d2 = cv[lane + 128] - q2;
        double d = d0 * d0 + d1 * d1 + d2 * d2;
        #pragma unroll
        for (int off = 32; off; off >>= 1) d += __shfl_xor(d, off);
        if (lane == t){ myd = d; mym = m; }
    }
    for (int r = 0; r < KNB; ++r){
        double bv = myd; int bi = mym;
        #pragma unroll
        for (int off = 32; off; off >>= 1){
            double ov = __shfl_xor(bv, off);
            int    oi = __shfl_xor(bi, off);
            if (ov < bv || (ov == bv && oi < bi)){ bv = ov; bi = oi; }
        }
        if (lane == 0) idxf[((size_t)b * NPT + q) * KNB + r] = bi;
        if (mym == bi){ myd = INFINITY; mym = 0x7fffffff; }
    }
}

// ---------------- gather + max-relative aggregate + channel interleave --------------------------
__global__ __launch_bounds__(256) void k_gather(
    const float* __restrict__ hbn, const int* __restrict__ idx, float* __restrict__ hcat)
{
    __shared__ int il[KNB * 256];
    const int tid = threadIdx.x;
    const int n0  = blockIdx.x * 256;
    const int cg  = blockIdx.y;
    const int b   = blockIdx.z;
    for (int lin = tid; lin < 256 * KNB; lin += 256){
        int nl = lin >> 4, k = lin & 15;
        il[k * 256 + nl] = idx[((size_t)b * NPT + n0) * KNB + lin];
    }
    __syncthreads();
    const float* base = hbn + (size_t)b * CH * NPT;
    const int n = n0 + tid;
    for (int c = cg * 48; c < cg * 48 + 48; ++c){
        const float* row = base + (size_t)c * NPT;
        float fi = row[n];
        float mx = -INFINITY;
        #pragma unroll
        for (int k = 0; k < KNB; ++k){
            float v = row[il[k * 256 + tid]];
            mx = fmaxf(mx, v - fi);
        }
        size_t o = ((size_t)b * 2 * CH + 2 * c) * NPT + n;
        hcat[o]       = fi;
        hcat[o + NPT] = mx;
    }
}

extern "C" void kernel_launch(void* const* d_in, const int* in_sizes, int n_in,
                              void* d_out, int out_size, void* d_ws, size_t ws_size,
                              hipStream_t stream)
{
    const float* x    = (const float*)d_in[0];
    const float* w1   = (const float*)d_in[1];
    const float* w2   = (const float*)d_in[2];
    const float* wmr  = (const float*)d_in[3];
    const float* bmr  = (const float*)d_in[4];
    const float* g0   = (const float*)d_in[5];
    const float* b0   = (const float*)d_in[6];
    const float* gm   = (const float*)d_in[7];
    const float* bm   = (const float*)d_in[8];
    const float* g1   = (const float*)d_in[9];
    const float* b1   = (const float*)d_in[10];
    float* outp = (float*)d_out;

    const size_t BCN = (size_t)BSZ * CH * NPT;
    float*  A     = (float*)d_ws;                       // BCN
    float*  Bb    = A + BCN;                            // BCN
    float*  Cc    = Bb + BCN;                           // 2*BCN floats
    double* t1d   = (double*)Cc;                        // BCN doubles (dead after k_tr64/refine)
    double* featT = (double*)(Cc + 2 * BCN);            // BCN doubles
    float*  sqv   = (float*)(featT + BCN);              // B*N
    int*    idx24 = (int*)(sqv + (size_t)BSZ * NPT);    // B*N*24
    int*    idxf  = idx24 + (size_t)BSZ * NPT * KPF;    // B*N*16
    double* scd   = (double*)(idxf + (size_t)BSZ * NPT * KNB);
    float*  scb   = (float*)(scd + CH);
    float *sc0 = scb,          *sh0 = scb + CH;
    float *sc1 = scb + 2 * CH, *sh1 = scb + 3 * CH;
    float *sc2 = scb + 4 * CH, *sh2 = scb + 5 * CH;

    dim3 gg(NPT / 1024, CH / 8, BSZ);
    dim3 ge(NPT / 1024, CH, BSZ);

    // fc1 (f64 accumulate, dual fp32/f64 write)
    k_fc1_f64<<<gg, 256, 0, stream>>>(x, w1, A, t1d);
    // BN0 stats in f64
    k_stats_f64<<<CH, 256, 0, stream>>>(t1d, g0, b0, sc0, sh0, scd);
    // f64 scaled transposed features for exact re-rank
    k_tr64<<<dim3(NPT / 32, CH / 32, BSZ), dim3(32, 8), 0, stream>>>(t1d, scd, featT);
    // fp32 BN0 apply
    k_affine<<<ge, 256, 0, stream>>>(A, sc0, sh0, Bb);
    // kNN: fp32 prefilter top-24 -> f64 exact top-16
    k_sq<<<dim3(NPT / 256, BSZ), 256, 0, stream>>>(Bb, sqv);
    k_knn24<<<dim3(NPT / 16, BSZ), 256, 0, stream>>>(Bb, sqv, idx24);
    k_refine<<<dim3(NPT, BSZ), 64, 0, stream>>>(featT, idx24, idxf);
    // gather/aggregate/interleave (overwrites t1d region; t1d is dead)
    k_gather<<<dim3(NPT / 256, 4, BSZ), 256, 0, stream>>>(Bb, idxf, Cc);
    // mr conv (K=384) + bias
    k_gemm<2 * CH, true, false, false><<<gg, 256, 0, stream>>>(Cc, wmr, bmr, nullptr, nullptr, nullptr, A);
    // BN1 stats, u = gelu(gelu(BN1(t2)))
    k_stats<<<CH, 256, 0, stream>>>(A, gm, bm, sc1, sh1);
    k_u<<<ge, 256, 0, stream>>>(A, sc1, sh1, Bb);
    // BN2 stats, fc2 with BN folded into input + residual
    k_stats<<<CH, 256, 0, stream>>>(Bb, g1, b1, sc2, sh2);
    k_gemm<CH, false, true, true><<<gg, 256, 0, stream>>>(Bb, w2, nullptr, sc2, sh2, x, outp);
}

// Round 3
// 1834.160 us; speedup vs baseline: 1.1519x; 1.1519x over previous
//
#include <hip/hip_runtime.h>
#include <hip/hip_bf16.h>
#include <math.h>

#define BSZ 4
#define CH  192
#define NPT 4096
#define KNB 16
#define KPF 24

typedef short short8 __attribute__((ext_vector_type(8)));
typedef float f32x4  __attribute__((ext_vector_type(4)));

__device__ __forceinline__ float gelu_exact(float x){
    return 0.5f * x * (1.0f + erff(x * 0.70710678118654752440f));
}

// ---------------- fp32 GEMM: out[b,o,n] = sum_c W[o,c] * in[b,c,n] (+bias)(+BN-fold)(+resid) ----
template<int KDIM, bool BIASED, bool SCALED, bool RESID>
__global__ __launch_bounds__(256) void k_gemm(
    const float* __restrict__ in, const float* __restrict__ W,
    const float* __restrict__ bias, const float* __restrict__ sc,
    const float* __restrict__ sh, const float* __restrict__ resid,
    float* __restrict__ out)
{
    constexpr int OT = 8, NT = 4;
    __shared__ float wtT[KDIM][OT];
    __shared__ float scl[SCALED ? KDIM : 1];
    __shared__ float shl[SCALED ? KDIM : 1];
    const int tid = threadIdx.x;
    const int o0  = blockIdx.y * OT;
    const int b   = blockIdx.z;
    const int n   = blockIdx.x * (256 * NT) + tid * NT;

    for (int lin = tid; lin < KDIM * OT; lin += 256){
        int c = lin >> 3, o = lin & 7;
        wtT[c][o] = W[(size_t)(o0 + o) * KDIM + c];
    }
    if (SCALED){
        for (int c = tid; c < KDIM; c += 256){ scl[c] = sc[c]; shl[c] = sh[c]; }
    }
    __syncthreads();

    float acc[OT][NT] = {};
    const float* ip = in + (size_t)b * KDIM * NPT + n;
    #pragma unroll 2
    for (int c = 0; c < KDIM; ++c){
        float4 x4 = *reinterpret_cast<const float4*>(ip + (size_t)c * NPT);
        float xv[NT] = {x4.x, x4.y, x4.z, x4.w};
        if (SCALED){
            #pragma unroll
            for (int j = 0; j < NT; ++j) xv[j] = fmaf(xv[j], scl[c], shl[c]);
        }
        float4 w0 = *reinterpret_cast<const float4*>(&wtT[c][0]);
        float4 w1 = *reinterpret_cast<const float4*>(&wtT[c][4]);
        float wv[OT] = {w0.x, w0.y, w0.z, w0.w, w1.x, w1.y, w1.z, w1.w};
        #pragma unroll
        for (int oo = 0; oo < OT; ++oo)
            #pragma unroll
            for (int j = 0; j < NT; ++j)
                acc[oo][j] = fmaf(wv[oo], xv[j], acc[oo][j]);
    }

    #pragma unroll
    for (int oo = 0; oo < OT; ++oo){
        size_t off = ((size_t)b * CH + o0 + oo) * NPT + n;
        float add = BIASED ? bias[o0 + oo] : 0.0f;
        float vals[4];
        #pragma unroll
        for (int j = 0; j < 4; ++j) vals[j] = acc[oo][j] + add;
        if (RESID){
            float4 r4 = *reinterpret_cast<const float4*>(resid + off);
            vals[0] += r4.x; vals[1] += r4.y; vals[2] += r4.z; vals[3] += r4.w;
        }
        float4 o4; o4.x = vals[0]; o4.y = vals[1]; o4.z = vals[2]; o4.w = vals[3];
        *reinterpret_cast<float4*>(out + off) = o4;
    }
}

// ---------------- fc1 with f64 accumulation: writes fp32 t1 and f64 t1 --------------------------
__global__ __launch_bounds__(256) void k_fc1_f64(
    const float* __restrict__ in, const float* __restrict__ W,
    float* __restrict__ outf, double* __restrict__ outd)
{
    constexpr int OT = 8, NT = 4;
    __shared__ float wtT[CH][OT];
    const int tid = threadIdx.x;
    const int o0  = blockIdx.y * OT;
    const int b   = blockIdx.z;
    const int n   = blockIdx.x * (256 * NT) + tid * NT;

    for (int lin = tid; lin < CH * OT; lin += 256){
        int c = lin >> 3, o = lin & 7;
        wtT[c][o] = W[(size_t)(o0 + o) * CH + c];
    }
    __syncthreads();

    double acc[OT][NT] = {};
    const float* ip = in + (size_t)b * CH * NPT + n;
    for (int c = 0; c < CH; ++c){
        float4 x4 = *reinterpret_cast<const float4*>(ip + (size_t)c * NPT);
        double xv[NT] = {x4.x, x4.y, x4.z, x4.w};
        float4 w0 = *reinterpret_cast<const float4*>(&wtT[c][0]);
        float4 w1 = *reinterpret_cast<const float4*>(&wtT[c][4]);
        double wv[OT] = {w0.x, w0.y, w0.z, w0.w, w1.x, w1.y, w1.z, w1.w};
        #pragma unroll
        for (int oo = 0; oo < OT; ++oo)
            #pragma unroll
            for (int j = 0; j < NT; ++j)
                acc[oo][j] = fma(wv[oo], xv[j], acc[oo][j]);
    }

    #pragma unroll
    for (int oo = 0; oo < OT; ++oo){
        size_t off = ((size_t)b * CH + o0 + oo) * NPT + n;
        #pragma unroll
        for (int j = 0; j < 4; ++j){
            outf[off + j] = (float)acc[oo][j];
            outd[off + j] = acc[oo][j];
        }
    }
}

// ---------------- f64 BN0 stats: fp32 scale/shift + f64 scale for kNN ---------------------------
__global__ __launch_bounds__(256) void k_stats_f64(
    const double* __restrict__ t, const float* __restrict__ gamma,
    const float* __restrict__ beta, float* __restrict__ scale,
    float* __restrict__ shift, double* __restrict__ scd)
{
    const int c = blockIdx.x, tid = threadIdx.x;
    double s = 0., s2 = 0.;
    for (int b = 0; b < BSZ; ++b){
        const double* p = t + ((size_t)b * CH + c) * NPT;
        for (int n = tid; n < NPT; n += 256){ double v = p[n]; s += v; s2 += v * v; }
    }
    __shared__ double rs[256], rs2[256];
    rs[tid] = s; rs2[tid] = s2; __syncthreads();
    for (int off = 128; off; off >>= 1){
        if (tid < off){ rs[tid] += rs[tid + off]; rs2[tid] += rs2[tid + off]; }
        __syncthreads();
    }
    if (tid == 0){
        const double invn = 1.0 / (BSZ * NPT);
        double mean = rs[0] * invn;
        double var  = rs2[0] * invn - mean * mean;
        double rstd = 1.0 / sqrt(var + 1e-5);
        double s_   = rstd * (double)gamma[c];
        scale[c] = (float)s_;
        shift[c] = (float)((double)beta[c] - mean * s_);
        scd[c]   = s_;
    }
}

// ---------------- fp32 per-channel batch stats -> scale/shift -----------------------------------
__global__ __launch_bounds__(256) void k_stats(
    const float* __restrict__ t, const float* __restrict__ gamma,
    const float* __restrict__ beta, float* __restrict__ scale, float* __restrict__ shift)
{
    const int c = blockIdx.x, tid = threadIdx.x;
    float s = 0.f, s2 = 0.f;
    for (int b = 0; b < BSZ; ++b){
        const float* p = t + ((size_t)b * CH + c) * NPT;
        for (int n = tid; n < NPT; n += 256){ float v = p[n]; s += v; s2 += v * v; }
    }
    __shared__ float rs[256], rs2[256];
    rs[tid] = s; rs2[tid] = s2; __syncthreads();
    for (int off = 128; off; off >>= 1){
        if (tid < off){ rs[tid] += rs[tid + off]; rs2[tid] += rs2[tid + off]; }
        __syncthreads();
    }
    if (tid == 0){
        const float invn = 1.0f / (BSZ * NPT);
        float mean = rs[0] * invn;
        float var  = rs2[0] * invn - mean * mean;
        float rstd = rsqrtf(var + 1e-5f);
        float s_   = rstd * gamma[c];
        scale[c] = s_;
        shift[c] = beta[c] - mean * s_;
    }
}

// ---------------- transpose + per-channel f64 scale: featT[b][n][c] -----------------------------
__global__ void k_tr64(const double* __restrict__ t1d, const double* __restrict__ scd,
                       double* __restrict__ featT)
{
    __shared__ double tile[32][33];
    const int n0 = blockIdx.x * 32, c0 = blockIdx.y * 32, b = blockIdx.z;
    #pragma unroll
    for (int r = 0; r < 32; r += 8){
        int c = c0 + threadIdx.y + r, n = n0 + threadIdx.x;
        tile[threadIdx.y + r][threadIdx.x] = t1d[((size_t)b * CH + c) * NPT + n] * scd[c];
    }
    __syncthreads();
    #pragma unroll
    for (int r = 0; r < 32; r += 8){
        int n = n0 + threadIdx.y + r, c = c0 + threadIdx.x;
        featT[((size_t)b * NPT + n) * CH + c] = tile[threadIdx.x][threadIdx.y + r];
    }
}

// ---------------- featT (f64, shift-free) -> bf16 features + fp32 sq norms ----------------------
__global__ __launch_bounds__(256) void k_bf_sq(
    const double* __restrict__ featT, unsigned short* __restrict__ featbf,
    float* __restrict__ sqv)
{
    const int wid  = threadIdx.x >> 6;
    const int lane = threadIdx.x & 63;
    const int row  = blockIdx.x * 4 + wid;
    const int b    = blockIdx.y;
    const double* p = featT + ((size_t)b * NPT + row) * CH;
    unsigned short* o = featbf + ((size_t)b * NPT + row) * CH;
    float s = 0.f;
    #pragma unroll
    for (int j = 0; j < 3; ++j){
        float v = (float)p[lane + 64 * j];
        s = fmaf(v, v, s);
        unsigned int bits = __builtin_bit_cast(unsigned int, v);
        o[lane + 64 * j] = (unsigned short)((bits + 0x7fff + ((bits >> 16) & 1)) >> 16);
    }
    #pragma unroll
    for (int off = 32; off; off >>= 1) s += __shfl_xor(s, off);
    if (lane == 0) sqv[b * NPT + row] = s;
}

// ---------------- elementwise BN apply / double-GELU(BN) ----------------------------------------
__global__ __launch_bounds__(256) void k_affine(
    const float* __restrict__ in, const float* __restrict__ sc,
    const float* __restrict__ sh, float* __restrict__ out)
{
    const int c = blockIdx.y, b = blockIdx.z;
    const int n = (blockIdx.x * 256 + threadIdx.x) * 4;
    size_t i = ((size_t)b * CH + c) * NPT + n;
    float4 v = *reinterpret_cast<const float4*>(in + i);
    float s = sc[c], t = sh[c];
    float4 o;
    o.x = fmaf(v.x, s, t); o.y = fmaf(v.y, s, t);
    o.z = fmaf(v.z, s, t); o.w = fmaf(v.w, s, t);
    *reinterpret_cast<float4*>(out + i) = o;
}

__global__ __launch_bounds__(256) void k_u(
    const float* __restrict__ in, const float* __restrict__ sc,
    const float* __restrict__ sh, float* __restrict__ out)
{
    const int c = blockIdx.y, b = blockIdx.z;
    const int n = (blockIdx.x * 256 + threadIdx.x) * 4;
    size_t i = ((size_t)b * CH + c) * NPT + n;
    float4 v = *reinterpret_cast<const float4*>(in + i);
    float s = sc[c], t = sh[c];
    float4 o;
    o.x = gelu_exact(gelu_exact(fmaf(v.x, s, t)));
    o.y = gelu_exact(gelu_exact(fmaf(v.y, s, t)));
    o.z = gelu_exact(gelu_exact(fmaf(v.z, s, t)));
    o.w = gelu_exact(gelu_exact(fmaf(v.w, s, t)));
    *reinterpret_cast<float4*>(out + i) = o;
}

// ---------------- MFMA kNN prefilter: bf16 Gram + per-lane top-24 -------------------------------
// 1 wave/block, 16 queries/wave. D layout: col(lane&15)=query, row((lane>>4)*4+i)=m.
__global__ __launch_bounds__(64) void k_knn_mfma(
    const unsigned short* __restrict__ featbf, const float* __restrict__ sqv,
    int* __restrict__ idx24)
{
    const int lane = threadIdx.x;
    const int r = lane & 15, g = lane >> 4;
    const int b  = blockIdx.y;
    const int q0 = blockIdx.x * 16;
    const unsigned short* fb = featbf + (size_t)b * NPT * CH;

    short8 bq[6];
    {
        const unsigned short* qp = fb + (size_t)(q0 + r) * CH + g * 8;
        #pragma unroll
        for (int ks = 0; ks < 6; ++ks)
            bq[ks] = *reinterpret_cast<const short8*>(qp + ks * 32);
    }

    float lv[KPF]; int li[KPF];
    #pragma unroll
    for (int e = 0; e < KPF; ++e){ lv[e] = INFINITY; li[e] = 0x7fffffff; }
    float mv = INFINITY; int mi = 0x7fffffff; int mp = 0;

    const float* sq = sqv + b * NPT;
    const unsigned short* pa = fb + (size_t)r * CH + g * 8;

    for (int m0 = 0; m0 < NPT; m0 += 32){
        const unsigned short* p0 = pa + (size_t)m0 * CH;
        const unsigned short* p1 = p0 + 16 * CH;
        short8 av0[6], av1[6];
        #pragma unroll
        for (int ks = 0; ks < 6; ++ks){
            av0[ks] = *reinterpret_cast<const short8*>(p0 + ks * 32);
            av1[ks] = *reinterpret_cast<const short8*>(p1 + ks * 32);
        }
        float4 s0 = *reinterpret_cast<const float4*>(sq + m0 + 4 * g);
        float4 s1 = *reinterpret_cast<const float4*>(sq + m0 + 16 + 4 * g);

        f32x4 acc0 = {0.f, 0.f, 0.f, 0.f};
        f32x4 acc1 = {0.f, 0.f, 0.f, 0.f};
        #pragma unroll
        for (int ks = 0; ks < 6; ++ks){
            acc0 = __builtin_amdgcn_mfma_f32_16x16x32_bf16(av0[ks], bq[ks], acc0, 0, 0, 0);
            acc1 = __builtin_amdgcn_mfma_f32_16x16x32_bf16(av1[ks], bq[ks], acc1, 0, 0, 0);
        }

        float sa[8] = {s0.x, s0.y, s0.z, s0.w, s1.x, s1.y, s1.z, s1.w};
        float dv[8]; int dm[8];
        #pragma unroll
        for (int i = 0; i < 4; ++i){
            dv[i]     = fmaf(-2.0f, acc0[i], sa[i]);
            dm[i]     = m0 + 4 * g + i;
            dv[i + 4] = fmaf(-2.0f, acc1[i], sa[i + 4]);
            dm[i + 4] = m0 + 16 + 4 * g + i;
        }
        #pragma unroll
        for (int u = 0; u < 8; ++u){
            float d = dv[u]; int m = dm[u];
            bool better = (d < mv) || (d == mv && m < mi);
            if (better){
                #pragma unroll
                for (int e = 0; e < KPF; ++e) if (e == mp){ lv[e] = d; li[e] = m; }
                mv = lv[0]; mi = li[0]; mp = 0;
                #pragma unroll
                for (int e = 1; e < KPF; ++e){
                    bool worse = (lv[e] > mv) || (lv[e] == mv && li[e] > mi);
                    if (worse){ mv = lv[e]; mi = li[e]; mp = e; }
                }
            }
        }
    }

    // merge the 4 lane-lists per query (lanes r, r+16, r+32, r+48), emit top-24
    for (int rd = 0; rd < KPF; ++rd){
        float bv = INFINITY; int bi = 0x7fffffff;
        #pragma unroll
        for (int e = 0; e < KPF; ++e){
            bool bet = (lv[e] < bv) || (lv[e] == bv && li[e] < bi);
            if (bet){ bv = lv[e]; bi = li[e]; }
        }
        #pragma unroll
        for (int off = 16; off <= 32; off <<= 1){
            float ov = __shfl_xor(bv, off);
            int   oi = __shfl_xor(bi, off);
            if (ov < bv || (ov == bv && oi < bi)){ bv = ov; bi = oi; }
        }
        if (g == 0) idx24[((size_t)b * NPT + q0 + r) * KPF + rd] = bi;
        #pragma unroll
        for (int e = 0; e < KPF; ++e) if (li[e] == bi){ lv[e] = INFINITY; li[e] = 0x7fffffff; }
    }
}

// ---------------- f64 re-rank of 24 candidates -> exact top-16 ----------------------------------
__global__ __launch_bounds__(64) void k_refine(
    const double* __restrict__ featT, const int* __restrict__ idx24, int* __restrict__ idxf)
{
    const int q = blockIdx.x, b = blockIdx.y, lane = threadIdx.x;
    const double* qv = featT + ((size_t)b * NPT + q) * CH;
    double q0 = qv[lane], q1 = qv[lane + 64], q2 = qv[lane + 128];
    double myd = INFINITY; int mym = 0x7fffffff;
    const int* cl = idx24 + ((size_t)b * NPT + q) * KPF;
    for (int t = 0; t < KPF; ++t){
        int m = cl[t];
        const double* cv = featT + ((size_t)b * NPT + m) * CH;
        double d0 = cv[lane] - q0, d1 = cv[lane + 64] - q1, d2 = cv[lane + 128] - q2;
        double d = d0 * d0 + d1 * d1 + d2 * d2;
        #pragma unroll
        for (int off = 32; off; off >>= 1) d += __shfl_xor(d, off);
        if (lane == t){ myd = d; mym = m; }
    }
    for (int r = 0; r < KNB; ++r){
        double bv = myd; int bi = mym;
        #pragma unroll
        for (int off = 32; off; off >>= 1){
            double ov = __shfl_xor(bv, off);
            int    oi = __shfl_xor(bi, off);
            if (ov < bv || (ov == bv && oi < bi)){ bv = ov; bi = oi; }
        }
        if (lane == 0) idxf[((size_t)b * NPT + q) * KNB + r] = bi;
        if (mym == bi){ myd = INFINITY; mym = 0x7fffffff; }
    }
}

// ---------------- gather + max-relative aggregate + channel interleave --------------------------
__global__ __launch_bounds__(256) void k_gather(
    const float* __restrict__ hbn, const int* __restrict__ idx, float* __restrict__ hcat)
{
    __shared__ int il[KNB * 256];
    const int tid = threadIdx.x;
    const int n0  = blockIdx.x * 256;
    const int cg  = blockIdx.y;
    const int b   = blockIdx.z;
    for (int lin = tid; lin < 256 * KNB; lin += 256){
        int nl = lin >> 4, k = lin & 15;
        il[k * 256 + nl] = idx[((size_t)b * NPT + n0) * KNB + lin];
    }
    __syncthreads();
    const float* base = hbn + (size_t)b * CH * NPT;
    const int n = n0 + tid;
    for (int c = cg * 48; c < cg * 48 + 48; ++c){
        const float* row = base + (size_t)c * NPT;
        float fi = row[n];
        float mx = -INFINITY;
        #pragma unroll
        for (int k = 0; k < KNB; ++k){
            float v = row[il[k * 256 + tid]];
            mx = fmaxf(mx, v - fi);
        }
        size_t o = ((size_t)b * 2 * CH + 2 * c) * NPT + n;
        hcat[o]       = fi;
        hcat[o + NPT] = mx;
    }
}

extern "C" void kernel_launch(void* const* d_in, const int* in_sizes, int n_in,
                              void* d_out, int out_size, void* d_ws, size_t ws_size,
                              hipStream_t stream)
{
    const float* x    = (const float*)d_in[0];
    const float* w1   = (const float*)d_in[1];
    const float* w2   = (const float*)d_in[2];
    const float* wmr  = (const float*)d_in[3];
    const float* bmr  = (const float*)d_in[4];
    const float* g0   = (const float*)d_in[5];
    const float* b0   = (const float*)d_in[6];
    const float* gm   = (const float*)d_in[7];
    const float* bm   = (const float*)d_in[8];
    const float* g1   = (const float*)d_in[9];
    const float* b1   = (const float*)d_in[10];
    float* outp = (float*)d_out;

    const size_t BCN = (size_t)BSZ * CH * NPT;
    float*  A     = (float*)d_ws;                       // BCN floats
    float*  Bb    = A + BCN;                            // BCN floats
    float*  Cc    = Bb + BCN;                           // 2*BCN floats
    double* t1d   = (double*)Cc;                        // BCN doubles (dead after k_tr64)
    unsigned short* featbf = (unsigned short*)Cc;       // BCN bf16 (alias; live knn only)
    double* featT = (double*)(Cc + 2 * BCN);            // BCN doubles
    float*  sqv   = (float*)(featT + BCN);              // B*N
    int*    idx24 = (int*)(sqv + (size_t)BSZ * NPT);    // B*N*24
    int*    idxf  = idx24 + (size_t)BSZ * NPT * KPF;    // B*N*16
    double* scd   = (double*)(idxf + (size_t)BSZ * NPT * KNB);
    float*  scb   = (float*)(scd + CH);
    float *sc0 = scb,          *sh0 = scb + CH;
    float *sc1 = scb + 2 * CH, *sh1 = scb + 3 * CH;
    float *sc2 = scb + 4 * CH, *sh2 = scb + 5 * CH;

    dim3 gg(NPT / 1024, CH / 8, BSZ);
    dim3 ge(NPT / 1024, CH, BSZ);

    // fc1 (f64 accumulate, dual fp32/f64 write)
    k_fc1_f64<<<gg, 256, 0, stream>>>(x, w1, A, t1d);
    // BN0 stats in f64
    k_stats_f64<<<CH, 256, 0, stream>>>(t1d, g0, b0, sc0, sh0, scd);
    // f64 scaled (shift-free) transposed features
    k_tr64<<<dim3(NPT / 32, CH / 32, BSZ), dim3(32, 8), 0, stream>>>(t1d, scd, featT);
    // bf16 features + fp32 sq norms (t1d dead; featbf overwrites it)
    k_bf_sq<<<dim3(NPT / 4, BSZ), 256, 0, stream>>>(featT, featbf, sqv);
    // fp32 BN0 apply
    k_affine<<<ge, 256, 0, stream>>>(A, sc0, sh0, Bb);
    // kNN: MFMA bf16 prefilter top-24 -> f64 exact top-16
    k_knn_mfma<<<dim3(NPT / 16, BSZ), 64, 0, stream>>>(featbf, sqv, idx24);
    k_refine<<<dim3(NPT, BSZ), 64, 0, stream>>>(featT, idx24, idxf);
    // gather/aggregate/interleave (overwrites featbf region; dead)
    k_gather<<<dim3(NPT / 256, 4, BSZ), 256, 0, stream>>>(Bb, idxf, Cc);
    // mr conv (K=384) + bias
    k_gemm<2 * CH, true, false, false><<<gg, 256, 0, stream>>>(Cc, wmr, bmr, nullptr, nullptr, nullptr, A);
    // BN1 stats, u = gelu(gelu(BN1(t2)))
    k_stats<<<CH, 256, 0, stream>>>(A, gm, bm, sc1, sh1);
    k_u<<<ge, 256, 0, stream>>>(A, sc1, sh1, Bb);
    // BN2 stats, fc2 with BN folded into input + residual
    k_stats<<<CH, 256, 0, stream>>>(Bb, g1, b1, sc2, sh2);
    k_gemm<CH, false, true, true><<<gg, 256, 0, stream>>>(Bb, w2, nullptr, sc2, sh2, x, outp);
}

// Round 4
// 594.671 us; speedup vs baseline: 3.5529x; 3.0843x over previous
//
#include <hip/hip_runtime.h>
#include <hip/hip_bf16.h>
#include <math.h>

#define BSZ 4
#define CH  192
#define NPT 4096
#define KNB 16
#define KPF 24

typedef short short8 __attribute__((ext_vector_type(8)));
typedef float f32x4  __attribute__((ext_vector_type(4)));

__device__ __forceinline__ float gelu_exact(float x){
    return 0.5f * x * (1.0f + erff(x * 0.70710678118654752440f));
}
__device__ __forceinline__ unsigned int umin_(unsigned int a, unsigned int b){ return a < b ? a : b; }
__device__ __forceinline__ unsigned int umax_(unsigned int a, unsigned int b){ return a < b ? b : a; }

// ---------------- fp32 GEMM: out[b,o,n] = sum_c W[o,c] * in[b,c,n] (+bias)(+BN-fold)(+resid) ----
template<int KDIM, bool BIASED, bool SCALED, bool RESID>
__global__ __launch_bounds__(256) void k_gemm(
    const float* __restrict__ in, const float* __restrict__ W,
    const float* __restrict__ bias, const float* __restrict__ sc,
    const float* __restrict__ sh, const float* __restrict__ resid,
    float* __restrict__ out)
{
    constexpr int OT = 8, NT = 4;
    __shared__ float wtT[KDIM][OT];
    __shared__ float scl[SCALED ? KDIM : 1];
    __shared__ float shl[SCALED ? KDIM : 1];
    const int tid = threadIdx.x;
    const int o0  = blockIdx.y * OT;
    const int b   = blockIdx.z;
    const int n   = blockIdx.x * (256 * NT) + tid * NT;

    for (int lin = tid; lin < KDIM * OT; lin += 256){
        int c = lin >> 3, o = lin & 7;
        wtT[c][o] = W[(size_t)(o0 + o) * KDIM + c];
    }
    if (SCALED){
        for (int c = tid; c < KDIM; c += 256){ scl[c] = sc[c]; shl[c] = sh[c]; }
    }
    __syncthreads();

    float acc[OT][NT] = {};
    const float* ip = in + (size_t)b * KDIM * NPT + n;
    #pragma unroll 2
    for (int c = 0; c < KDIM; ++c){
        float4 x4 = *reinterpret_cast<const float4*>(ip + (size_t)c * NPT);
        float xv[NT] = {x4.x, x4.y, x4.z, x4.w};
        if (SCALED){
            #pragma unroll
            for (int j = 0; j < NT; ++j) xv[j] = fmaf(xv[j], scl[c], shl[c]);
        }
        float4 w0 = *reinterpret_cast<const float4*>(&wtT[c][0]);
        float4 w1 = *reinterpret_cast<const float4*>(&wtT[c][4]);
        float wv[OT] = {w0.x, w0.y, w0.z, w0.w, w1.x, w1.y, w1.z, w1.w};
        #pragma unroll
        for (int oo = 0; oo < OT; ++oo)
            #pragma unroll
            for (int j = 0; j < NT; ++j)
                acc[oo][j] = fmaf(wv[oo], xv[j], acc[oo][j]);
    }

    #pragma unroll
    for (int oo = 0; oo < OT; ++oo){
        size_t off = ((size_t)b * CH + o0 + oo) * NPT + n;
        float add = BIASED ? bias[o0 + oo] : 0.0f;
        float vals[4];
        #pragma unroll
        for (int j = 0; j < 4; ++j) vals[j] = acc[oo][j] + add;
        if (RESID){
            float4 r4 = *reinterpret_cast<const float4*>(resid + off);
            vals[0] += r4.x; vals[1] += r4.y; vals[2] += r4.z; vals[3] += r4.w;
        }
        float4 o4; o4.x = vals[0]; o4.y = vals[1]; o4.z = vals[2]; o4.w = vals[3];
        *reinterpret_cast<float4*>(out + off) = o4;
    }
}

// ---------------- fc1 with f64 accumulation: writes fp32 t1 and f64 t1 --------------------------
__global__ __launch_bounds__(256) void k_fc1_f64(
    const float* __restrict__ in, const float* __restrict__ W,
    float* __restrict__ outf, double* __restrict__ outd)
{
    constexpr int OT = 8, NT = 4;
    __shared__ float wtT[CH][OT];
    const int tid = threadIdx.x;
    const int o0  = blockIdx.y * OT;
    const int b   = blockIdx.z;
    const int n   = blockIdx.x * (256 * NT) + tid * NT;

    for (int lin = tid; lin < CH * OT; lin += 256){
        int c = lin >> 3, o = lin & 7;
        wtT[c][o] = W[(size_t)(o0 + o) * CH + c];
    }
    __syncthreads();

    double acc[OT][NT] = {};
    const float* ip = in + (size_t)b * CH * NPT + n;
    for (int c = 0; c < CH; ++c){
        float4 x4 = *reinterpret_cast<const float4*>(ip + (size_t)c * NPT);
        double xv[NT] = {x4.x, x4.y, x4.z, x4.w};
        float4 w0 = *reinterpret_cast<const float4*>(&wtT[c][0]);
        float4 w1 = *reinterpret_cast<const float4*>(&wtT[c][4]);
        double wv[OT] = {w0.x, w0.y, w0.z, w0.w, w1.x, w1.y, w1.z, w1.w};
        #pragma unroll
        for (int oo = 0; oo < OT; ++oo)
            #pragma unroll
            for (int j = 0; j < NT; ++j)
                acc[oo][j] = fma(wv[oo], xv[j], acc[oo][j]);
    }

    #pragma unroll
    for (int oo = 0; oo < OT; ++oo){
        size_t off = ((size_t)b * CH + o0 + oo) * NPT + n;
        #pragma unroll
        for (int j = 0; j < 4; ++j){
            outf[off + j] = (float)acc[oo][j];
            outd[off + j] = acc[oo][j];
        }
    }
}

// ---------------- f64 BN0 stats: fp32 scale/shift + f64 scale for kNN ---------------------------
__global__ __launch_bounds__(256) void k_stats_f64(
    const double* __restrict__ t, const float* __restrict__ gamma,
    const float* __restrict__ beta, float* __restrict__ scale,
    float* __restrict__ shift, double* __restrict__ scd)
{
    const int c = blockIdx.x, tid = threadIdx.x;
    double s = 0., s2 = 0.;
    for (int b = 0; b < BSZ; ++b){
        const double* p = t + ((size_t)b * CH + c) * NPT;
        for (int n = tid; n < NPT; n += 256){ double v = p[n]; s += v; s2 += v * v; }
    }
    __shared__ double rs[256], rs2[256];
    rs[tid] = s; rs2[tid] = s2; __syncthreads();
    for (int off = 128; off; off >>= 1){
        if (tid < off){ rs[tid] += rs[tid + off]; rs2[tid] += rs2[tid + off]; }
        __syncthreads();
    }
    if (tid == 0){
        const double invn = 1.0 / (BSZ * NPT);
        double mean = rs[0] * invn;
        double var  = rs2[0] * invn - mean * mean;
        double rstd = 1.0 / sqrt(var + 1e-5);
        double s_   = rstd * (double)gamma[c];
        scale[c] = (float)s_;
        shift[c] = (float)((double)beta[c] - mean * s_);
        scd[c]   = s_;
    }
}

// ---------------- fp32 per-channel batch stats -> scale/shift -----------------------------------
__global__ __launch_bounds__(256) void k_stats(
    const float* __restrict__ t, const float* __restrict__ gamma,
    const float* __restrict__ beta, float* __restrict__ scale, float* __restrict__ shift)
{
    const int c = blockIdx.x, tid = threadIdx.x;
    float s = 0.f, s2 = 0.f;
    for (int b = 0; b < BSZ; ++b){
        const float* p = t + ((size_t)b * CH + c) * NPT;
        for (int n = tid; n < NPT; n += 256){ float v = p[n]; s += v; s2 += v * v; }
    }
    __shared__ float rs[256], rs2[256];
    rs[tid] = s; rs2[tid] = s2; __syncthreads();
    for (int off = 128; off; off >>= 1){
        if (tid < off){ rs[tid] += rs[tid + off]; rs2[tid] += rs2[tid + off]; }
        __syncthreads();
    }
    if (tid == 0){
        const float invn = 1.0f / (BSZ * NPT);
        float mean = rs[0] * invn;
        float var  = rs2[0] * invn - mean * mean;
        float rstd = rsqrtf(var + 1e-5f);
        float s_   = rstd * gamma[c];
        scale[c] = s_;
        shift[c] = beta[c] - mean * s_;
    }
}

// ---------------- transpose + per-channel f64 scale: featT[b][n][c] -----------------------------
__global__ void k_tr64(const double* __restrict__ t1d, const double* __restrict__ scd,
                       double* __restrict__ featT)
{
    __shared__ double tile[32][33];
    const int n0 = blockIdx.x * 32, c0 = blockIdx.y * 32, b = blockIdx.z;
    #pragma unroll
    for (int r = 0; r < 32; r += 8){
        int c = c0 + threadIdx.y + r, n = n0 + threadIdx.x;
        tile[threadIdx.y + r][threadIdx.x] = t1d[((size_t)b * CH + c) * NPT + n] * scd[c];
    }
    __syncthreads();
    #pragma unroll
    for (int r = 0; r < 32; r += 8){
        int n = n0 + threadIdx.y + r, c = c0 + threadIdx.x;
        featT[((size_t)b * NPT + n) * CH + c] = tile[threadIdx.x][threadIdx.y + r];
    }
}

// ---------------- featT (f64, shift-free) -> bf16 features + fp32 sq norms ----------------------
__global__ __launch_bounds__(256) void k_bf_sq(
    const double* __restrict__ featT, unsigned short* __restrict__ featbf,
    float* __restrict__ sqv)
{
    const int wid  = threadIdx.x >> 6;
    const int lane = threadIdx.x & 63;
    const int row  = blockIdx.x * 4 + wid;
    const int b    = blockIdx.y;
    const double* p = featT + ((size_t)b * NPT + row) * CH;
    unsigned short* o = featbf + ((size_t)b * NPT + row) * CH;
    float s = 0.f;
    #pragma unroll
    for (int j = 0; j < 3; ++j){
        float v = (float)p[lane + 64 * j];
        s = fmaf(v, v, s);
        unsigned int bits = __builtin_bit_cast(unsigned int, v);
        o[lane + 64 * j] = (unsigned short)((bits + 0x7fff + ((bits >> 16) & 1)) >> 16);
    }
    #pragma unroll
    for (int off = 32; off; off >>= 1) s += __shfl_xor(s, off);
    if (lane == 0) sqv[b * NPT + row] = s;
}

// ---------------- elementwise BN apply / double-GELU(BN) ----------------------------------------
__global__ __launch_bounds__(256) void k_affine(
    const float* __restrict__ in, const float* __restrict__ sc,
    const float* __restrict__ sh, float* __restrict__ out)
{
    const int c = blockIdx.y, b = blockIdx.z;
    const int n = (blockIdx.x * 256 + threadIdx.x) * 4;
    size_t i = ((size_t)b * CH + c) * NPT + n;
    float4 v = *reinterpret_cast<const float4*>(in + i);
    float s = sc[c], t = sh[c];
    float4 o;
    o.x = fmaf(v.x, s, t); o.y = fmaf(v.y, s, t);
    o.z = fmaf(v.z, s, t); o.w = fmaf(v.w, s, t);
    *reinterpret_cast<float4*>(out + i) = o;
}

__global__ __launch_bounds__(256) void k_u(
    const float* __restrict__ in, const float* __restrict__ sc,
    const float* __restrict__ sh, float* __restrict__ out)
{
    const int c = blockIdx.y, b = blockIdx.z;
    const int n = (blockIdx.x * 256 + threadIdx.x) * 4;
    size_t i = ((size_t)b * CH + c) * NPT + n;
    float4 v = *reinterpret_cast<const float4*>(in + i);
    float s = sc[c], t = sh[c];
    float4 o;
    o.x = gelu_exact(gelu_exact(fmaf(v.x, s, t)));
    o.y = gelu_exact(gelu_exact(fmaf(v.y, s, t)));
    o.z = gelu_exact(gelu_exact(fmaf(v.z, s, t)));
    o.w = gelu_exact(gelu_exact(fmaf(v.w, s, t)));
    *reinterpret_cast<float4*>(out + i) = o;
}

// ---------------- MFMA kNN prefilter: bf16 Gram + branchless packed-key top-k -------------------
// 2 waves/block over disjoint m-tiles; 16 queries/block.
// MFMA D layout: col(lane&15)=query, row((lane>>4)*4+i)=m within 16-tile.
// key = sortable-u32(distance) top 20 bits | candidate index (12 bits).
__global__ __launch_bounds__(128) void k_knn_mfma(
    const unsigned short* __restrict__ featbf, const float* __restrict__ sqv,
    int* __restrict__ idx24)
{
    __shared__ unsigned int mlist[2][16][KPF];
    const int tid  = threadIdx.x;
    const int wv   = tid >> 6;
    const int lane = tid & 63;
    const int r = lane & 15, g = lane >> 4;
    const int b  = blockIdx.y;
    const int q0 = blockIdx.x * 16;
    const unsigned short* fb = featbf + (size_t)b * NPT * CH;

    short8 bq[6];
    {
        const unsigned short* qp = fb + (size_t)(q0 + r) * CH + g * 8;
        #pragma unroll
        for (int ks = 0; ks < 6; ++ks)
            bq[ks] = *reinterpret_cast<const short8*>(qp + ks * 32);
    }

    unsigned int Q[16];
    #pragma unroll
    for (int e = 0; e < 16; ++e) Q[e] = 0xFFFFFFFFu;

    const float* sq = sqv + b * NPT;
    const unsigned short* pa = fb + (size_t)r * CH + g * 8;

    for (int m0 = wv * 32; m0 < NPT; m0 += 64){
        const unsigned short* p0 = pa + (size_t)m0 * CH;
        const unsigned short* p1 = p0 + 16 * CH;
        short8 av0[6], av1[6];
        #pragma unroll
        for (int ks = 0; ks < 6; ++ks){
            av0[ks] = *reinterpret_cast<const short8*>(p0 + ks * 32);
            av1[ks] = *reinterpret_cast<const short8*>(p1 + ks * 32);
        }
        float4 s0 = *reinterpret_cast<const float4*>(sq + m0 + 4 * g);
        float4 s1 = *reinterpret_cast<const float4*>(sq + m0 + 16 + 4 * g);

        f32x4 acc0 = {0.f, 0.f, 0.f, 0.f};
        f32x4 acc1 = {0.f, 0.f, 0.f, 0.f};
        #pragma unroll
        for (int ks = 0; ks < 6; ++ks){
            acc0 = __builtin_amdgcn_mfma_f32_16x16x32_bf16(av0[ks], bq[ks], acc0, 0, 0, 0);
            acc1 = __builtin_amdgcn_mfma_f32_16x16x32_bf16(av1[ks], bq[ks], acc1, 0, 0, 0);
        }

        float sa[8] = {s0.x, s0.y, s0.z, s0.w, s1.x, s1.y, s1.z, s1.w};
        #pragma unroll
        for (int u = 0; u < 8; ++u){
            float d = fmaf(-2.0f, (u < 4) ? acc0[u & 3] : acc1[u & 3], sa[u]);
            int   m = m0 + ((u < 4) ? 0 : 16) + 4 * g + (u & 3);
            int bb = __builtin_bit_cast(int, d);
            unsigned int uu = (unsigned int)(bb ^ ((bb >> 31) | 0x80000000));
            unsigned int k  = (uu & 0xFFFFF000u) | (unsigned int)m;
            // branchless sorted bubble insert (ascending, Q[15] = worst)
            #pragma unroll
            for (int e = 0; e < 16; ++e){
                unsigned int qe = Q[e];
                Q[e] = umin_(k, qe);
                k    = umax_(k, qe);
            }
        }
    }

    // per-wave extraction: 24 rounds of 4-lane min + winner shift (keys unique)
    for (int rd = 0; rd < KPF; ++rd){
        unsigned int v = Q[0];
        v = umin_(v, (unsigned int)__shfl_xor((int)v, 16));
        v = umin_(v, (unsigned int)__shfl_xor((int)v, 32));
        bool win = (Q[0] == v);
        if (win){
            #pragma unroll
            for (int e = 0; e < 15; ++e) Q[e] = Q[e + 1];
            Q[15] = 0xFFFFFFFFu;
        }
        if (g == 0) mlist[wv][r][rd] = v;
    }
    __syncthreads();

    // merge the two sorted 24-lists per query -> top-24 indices
    if (tid < 16){
        const int q = tid;
        int ia = 0, ib = 0;
        int* op = idx24 + ((size_t)b * NPT + q0 + q) * KPF;
        for (int rd = 0; rd < KPF; ++rd){
            unsigned int ka = mlist[0][q][ia];
            unsigned int kb = mlist[1][q][ib];
            bool ta = ka <= kb;
            op[rd] = (int)((ta ? ka : kb) & 0xFFFu);
            ia += ta ? 1 : 0; ib += ta ? 0 : 1;
        }
    }
}

// ---------------- f64 re-rank of 24 candidates -> exact top-16 ----------------------------------
__global__ __launch_bounds__(64) void k_refine(
    const double* __restrict__ featT, const int* __restrict__ idx24, int* __restrict__ idxf)
{
    const int q = blockIdx.x, b = blockIdx.y, lane = threadIdx.x;
    const double* qv = featT + ((size_t)b * NPT + q) * CH;
    double q0 = qv[lane], q1 = qv[lane + 64], q2 = qv[lane + 128];
    double myd = INFINITY; int mym = 0x7fffffff;
    const int* cl = idx24 + ((size_t)b * NPT + q) * KPF;
    for (int t = 0; t < KPF; ++t){
        int m = cl[t];
        const double* cv = featT + ((size_t)b * NPT + m) * CH;
        double d0 = cv[lane] - q0, d1 = cv[lane + 64] - q1, d2 = cv[lane + 128] - q2;
        double d = d0 * d0 + d1 * d1 + d2 * d2;
        #pragma unroll
        for (int off = 32; off; off >>= 1) d += __shfl_xor(d, off);
        if (lane == t){ myd = d; mym = m; }
    }
    for (int r = 0; r < KNB; ++r){
        double bv = myd; int bi = mym;
        #pragma unroll
        for (int off = 32; off; off >>= 1){
            double ov = __shfl_xor(bv, off);
            int    oi = __shfl_xor(bi, off);
            if (ov < bv || (ov == bv && oi < bi)){ bv = ov; bi = oi; }
        }
        if (lane == 0) idxf[((size_t)b * NPT + q) * KNB + r] = bi;
        if (mym == bi){ myd = INFINITY; mym = 0x7fffffff; }
    }
}

// ---------------- gather + max-relative aggregate + channel interleave --------------------------
__global__ __launch_bounds__(256) void k_gather(
    const float* __restrict__ hbn, const int* __restrict__ idx, float* __restrict__ hcat)
{
    __shared__ int il[KNB * 256];
    const int tid = threadIdx.x;
    const int n0  = blockIdx.x * 256;
    const int cg  = blockIdx.y;
    const int b   = blockIdx.z;
    for (int lin = tid; lin < 256 * KNB; lin += 256){
        int nl = lin >> 4, k = lin & 15;
        il[k * 256 + nl] = idx[((size_t)b * NPT + n0) * KNB + lin];
    }
    __syncthreads();
    const float* base = hbn + (size_t)b * CH * NPT;
    const int n = n0 + tid;
    for (int c = cg * 48; c < cg * 48 + 48; ++c){
        const float* row = base + (size_t)c * NPT;
        float fi = row[n];
        float mx = -INFINITY;
        #pragma unroll
        for (int k = 0; k < KNB; ++k){
            float v = row[il[k * 256 + tid]];
            mx = fmaxf(mx, v - fi);
        }
        size_t o = ((size_t)b * 2 * CH + 2 * c) * NPT + n;
        hcat[o]       = fi;
        hcat[o + NPT] = mx;
    }
}

extern "C" void kernel_launch(void* const* d_in, const int* in_sizes, int n_in,
                              void* d_out, int out_size, void* d_ws, size_t ws_size,
                              hipStream_t stream)
{
    const float* x    = (const float*)d_in[0];
    const float* w1   = (const float*)d_in[1];
    const float* w2   = (const float*)d_in[2];
    const float* wmr  = (const float*)d_in[3];
    const float* bmr  = (const float*)d_in[4];
    const float* g0   = (const float*)d_in[5];
    const float* b0   = (const float*)d_in[6];
    const float* gm   = (const float*)d_in[7];
    const float* bm   = (const float*)d_in[8];
    const float* g1   = (const float*)d_in[9];
    const float* b1   = (const float*)d_in[10];
    float* outp = (float*)d_out;

    const size_t BCN = (size_t)BSZ * CH * NPT;
    float*  A     = (float*)d_ws;                       // BCN floats
    float*  Bb    = A + BCN;                            // BCN floats
    float*  Cc    = Bb + BCN;                           // 2*BCN floats
    double* t1d   = (double*)Cc;                        // BCN doubles (dead after k_tr64)
    unsigned short* featbf = (unsigned short*)Cc;       // BCN bf16 (alias; live knn only)
    double* featT = (double*)(Cc + 2 * BCN);            // BCN doubles
    float*  sqv   = (float*)(featT + BCN);              // B*N
    int*    idx24 = (int*)(sqv + (size_t)BSZ * NPT);    // B*N*24
    int*    idxf  = idx24 + (size_t)BSZ * NPT * KPF;    // B*N*16
    double* scd   = (double*)(idxf + (size_t)BSZ * NPT * KNB);
    float*  scb   = (float*)(scd + CH);
    float *sc0 = scb,          *sh0 = scb + CH;
    float *sc1 = scb + 2 * CH, *sh1 = scb + 3 * CH;
    float *sc2 = scb + 4 * CH, *sh2 = scb + 5 * CH;

    dim3 gg(NPT / 1024, CH / 8, BSZ);
    dim3 ge(NPT / 1024, CH, BSZ);

    // fc1 (f64 accumulate, dual fp32/f64 write)
    k_fc1_f64<<<gg, 256, 0, stream>>>(x, w1, A, t1d);
    // BN0 stats in f64
    k_stats_f64<<<CH, 256, 0, stream>>>(t1d, g0, b0, sc0, sh0, scd);
    // f64 scaled (shift-free) transposed features
    k_tr64<<<dim3(NPT / 32, CH / 32, BSZ), dim3(32, 8), 0, stream>>>(t1d, scd, featT);
    // bf16 features + fp32 sq norms (t1d dead; featbf overwrites it)
    k_bf_sq<<<dim3(NPT / 4, BSZ), 256, 0, stream>>>(featT, featbf, sqv);
    // fp32 BN0 apply
    k_affine<<<ge, 256, 0, stream>>>(A, sc0, sh0, Bb);
    // kNN: MFMA bf16 prefilter top-24 (branchless packed-key select) -> f64 exact top-16
    k_knn_mfma<<<dim3(NPT / 16, BSZ), 128, 0, stream>>>(featbf, sqv, idx24);
    k_refine<<<dim3(NPT, BSZ), 64, 0, stream>>>(featT, idx24, idxf);
    // gather/aggregate/interleave (overwrites featbf region; dead)
    k_gather<<<dim3(NPT / 256, 4, BSZ), 256, 0, stream>>>(Bb, idxf, Cc);
    // mr conv (K=384) + bias
    k_gemm<2 * CH, true, false, false><<<gg, 256, 0, stream>>>(Cc, wmr, bmr, nullptr, nullptr, nullptr, A);
    // BN1 stats, u = gelu(gelu(BN1(t2)))
    k_stats<<<CH, 256, 0, stream>>>(A, gm, bm, sc1, sh1);
    k_u<<<ge, 256, 0, stream>>>(A, sc1, sh1, Bb);
    // BN2 stats, fc2 with BN folded into input + residual
    k_stats<<<CH, 256, 0, stream>>>(Bb, g1, b1, sc2, sh2);
    k_gemm<CH, false, true, true><<<gg, 256, 0, stream>>>(Bb, w2, nullptr, sc2, sh2, x, outp);
}